// Round 6
// baseline (62.706 us; speedup 1.0000x reference)
//
#include <hip/hip_runtime.h>
#include <math.h>

#define CLIPV 0.03f

struct W9 { float g[9]; };

__device__ __forceinline__ int reflect_idx(int i, int n) {
    if (i < 0) i = -i;
    if (i >= n) i = 2 * n - 2 - i;
    return i;
}

__device__ __forceinline__ float4 shfl_up1(float4 v) {
    float4 r;
    r.x = __shfl_up(v.x, 1); r.y = __shfl_up(v.y, 1);
    r.z = __shfl_up(v.z, 1); r.w = __shfl_up(v.w, 1);
    return r;
}
__device__ __forceinline__ float4 shfl_dn1(float4 v) {
    float4 r;
    r.x = __shfl_down(v.x, 1); r.y = __shfl_down(v.y, 1);
    r.z = __shfl_down(v.z, 1); r.w = __shfl_down(v.w, 1);
    return r;
}

// ---------------------------------------------------------------------------
// Pass 1: W-conv + H-conv. Zero LDS, zero barriers, one f4 load per lane-step.
// One wave = one (z-plane, 16-row h-chunk); wave covers the full 256-col row
// (64 lanes x float4). Per h-step: 1 float4 load (2-deep pipelined), W-window
// from own f4 + __shfl neighbors (edge lanes 0/63 get reflected cols from
// {own,neighbor} registers via selects), W-conv, 9-deep f4 H-ring (full
// unroll => static indices), H-conv, f4 store.
// Grid: 1024 blocks x 4 waves = 4096 waves = 16 waves/CU.
// XCD swizzle: bid&7 = XCD owns z-band [32*xcd, 32*xcd+32).
// ---------------------------------------------------------------------------
__global__ __launch_bounds__(256) void wh_pass(const float* __restrict__ x,
                                               float* __restrict__ tmp, W9 wt) {
    const int bid = blockIdx.x;
    const int xcd = bid & 7;
    const int k   = bid >> 3;              // 0..127
    const int z   = xcd * 32 + (k >> 2);   // XCD-local z band
    const int q   = k & 3;
    const int wv  = threadIdx.x >> 6;
    const int h0  = (q * 4 + wv) * 16;     // this wave's 16 output rows
    const int L   = threadIdx.x & 63;
    const int w4  = L * 4;
    const bool l0 = (L == 0), l63 = (L == 63);

    const float* plane  = x   + (size_t)z * 65536;
    float*       oplane = tmp + (size_t)z * 65536;

    float4 ring[9];

    // 2-deep load pipeline
    float4 cur = *(const float4*)(plane + reflect_idx(h0 - 4, 256) * 256 + w4);
    float4 nxt = *(const float4*)(plane + reflect_idx(h0 - 3, 256) * 256 + w4);

    #pragma unroll
    for (int i = 0; i < 24; ++i) {
        float4 nn;
        if (i < 22)
            nn = *(const float4*)(plane + reflect_idx(h0 - 2 + i, 256) * 256 + w4);

        const float4 Cf = cur;
        const float4 Lf = shfl_up1(cur);   // lane L-1's f4 (cols w-4..w-1)
        const float4 Rf = shfl_dn1(cur);   // lane L+1's f4 (cols w+4..w+7)

        float sv[12];
        sv[0] = l0 ? Rf.x : Lf.x;   // col -4 -> 4
        sv[1] = l0 ? Cf.w : Lf.y;   // col -3 -> 3
        sv[2] = l0 ? Cf.z : Lf.z;   // col -2 -> 2
        sv[3] = l0 ? Cf.y : Lf.w;   // col -1 -> 1
        sv[4] = Cf.x; sv[5] = Cf.y; sv[6] = Cf.z; sv[7] = Cf.w;
        sv[8]  = l63 ? Cf.z : Rf.x; // col 256 -> 254
        sv[9]  = l63 ? Cf.y : Rf.y; // col 257 -> 253
        sv[10] = l63 ? Cf.x : Rf.z; // col 258 -> 252
        sv[11] = l63 ? Lf.w : Rf.w; // col 259 -> 251

        // W-conv -> one float4
        float4 wc;
        {
            float a0 = 0.f, a1 = 0.f, a2 = 0.f, a3 = 0.f;
            #pragma unroll
            for (int j = 0; j < 9; ++j) {
                a0 = fmaf(wt.g[j], sv[j],     a0);
                a1 = fmaf(wt.g[j], sv[j + 1], a1);
                a2 = fmaf(wt.g[j], sv[j + 2], a2);
                a3 = fmaf(wt.g[j], sv[j + 3], a3);
            }
            wc.x = a0; wc.y = a1; wc.z = a2; wc.w = a3;
        }
        ring[i % 9] = wc;   // static after full unroll

        // H-conv once ring holds rows hout-4..hout+4
        if (i >= 8) {
            float a0 = 0.f, a1 = 0.f, a2 = 0.f, a3 = 0.f;
            #pragma unroll
            for (int j = 0; j < 9; ++j) {
                const float4 v = ring[(i - 8 + j) % 9];
                a0 = fmaf(wt.g[j], v.x, a0);
                a1 = fmaf(wt.g[j], v.y, a1);
                a2 = fmaf(wt.g[j], v.z, a2);
                a3 = fmaf(wt.g[j], v.w, a3);
            }
            float4 o; o.x = a0; o.y = a1; o.z = a2; o.w = a3;
            *(float4*)(oplane + (h0 + i - 8) * 256 + w4) = o;
        }

        cur = nxt; nxt = nn;
    }
}

// ---------------------------------------------------------------------------
// Pass 2: D-conv + clip (unchanged from R5 — measured ~free). Thread owns one
// float4 column, marches a z-chunk of 16 planes with a 9-deep f4 ring.
// Grid: 1024 blocks; chunk -> XCD mapping matches pass 1 (XCD-local tmp).
// ---------------------------------------------------------------------------
__global__ __launch_bounds__(256) void d_clip_pass(const float* __restrict__ tmp,
                                                   const float* __restrict__ x,
                                                   float* __restrict__ out, W9 wt) {
    const int bid   = blockIdx.x;                         // 0..1023
    const int chunk = (bid & 7) * 2 + ((bid >> 3) & 1);   // 0..15 (XCD-local)
    const int tile  = bid >> 4;                           // 0..63
    const int z0    = chunk * 16;
    const size_t c4 = (size_t)tile * 256 + threadIdx.x;   // f4 index in plane

    const float4* t4 = (const float4*)tmp;
    const float4* xp = (const float4*)x;
    float4*       o4 = (float4*)out;

    float4 ring[9];
    #pragma unroll
    for (int kk = 0; kk < 8; ++kk)
        ring[kk] = t4[(size_t)reflect_idx(z0 - 4 + kk, 256) * 16384 + c4];

    #pragma unroll
    for (int i = 0; i < 16; ++i) {
        const int z = z0 + i;
        ring[(8 + i) % 9] = t4[(size_t)reflect_idx(z + 4, 256) * 16384 + c4];
        const float4 xv = xp[(size_t)z * 16384 + c4];

        float a0 = 0.f, a1 = 0.f, a2 = 0.f, a3 = 0.f;
        #pragma unroll
        for (int j = 0; j < 9; ++j) {
            const float4 v = ring[(i + j) % 9];
            a0 = fmaf(wt.g[j], v.x, a0);
            a1 = fmaf(wt.g[j], v.y, a1);
            a2 = fmaf(wt.g[j], v.z, a2);
            a3 = fmaf(wt.g[j], v.w, a3);
        }
        float4 r;
        r.x = fmaxf(fminf(xv.x, a0 + CLIPV), a0 - CLIPV);
        r.y = fmaxf(fminf(xv.y, a1 + CLIPV), a1 - CLIPV);
        r.z = fmaxf(fminf(xv.z, a2 + CLIPV), a2 - CLIPV);
        r.w = fmaxf(fminf(xv.w, a3 + CLIPV), a3 - CLIPV);
        o4[(size_t)z * 16384 + c4] = r;
    }
}

extern "C" void kernel_launch(void* const* d_in, const int* in_sizes, int n_in,
                              void* d_out, int out_size, void* d_ws, size_t ws_size,
                              hipStream_t stream) {
    const float* x = (const float*)d_in[0];
    float* out = (float*)d_out;
    float* tmp = (float*)d_ws;   // 64 MB

    // normalized 1-D Gaussian weights (separable form of the reference kernel)
    W9 wt;
    {
        double g[9], s = 0.0;
        const double sigma = 9.0 / 4.0;
        for (int i = 0; i < 9; ++i) {
            double tt = (i - 4.0) / sigma;
            g[i] = exp(-0.5 * tt * tt);
            s += g[i];
        }
        for (int i = 0; i < 9; ++i) wt.g[i] = (float)(g[i] / s);
    }

    wh_pass<<<dim3(1024), dim3(256), 0, stream>>>(x, tmp, wt);
    d_clip_pass<<<dim3(1024), dim3(256), 0, stream>>>(tmp, x, out, wt);
}